// Round 1
// baseline (148.526 us; speedup 1.0000x reference)
//
#include <hip/hip_runtime.h>
#include <math.h>

// SSIM loss, fp32 in, B=16 C=3 H=W=512, 11x11 Gaussian (sigma=1.5), zero pad.
// R10: move both separable conv passes onto the (previously idle) MFMA pipe.
//   Horizontal: D[16r][16u] = A(input rows, 16x32) x Wh(32x16, banded: w[t-u-3])
//   Vertical:   D[16u][16c] = Wv(16x32, banded: w[t-u]) x B(H rows, 32x16)
// 4 conv planes (S=x+y, D=x-y, S2, D2) as in R9; S2/D2 A-fragments are
// in-register v_pk_mul_f16 squares of the S/D fragments, so LDS stages only
// s,d (f16) plus a TRANSPOSED f16 H buffer (column-major -> vertical
// B-fragments are single ds_read_b128).
// gfx950 v_mfma_f32_16x16x32_f16 layouts:
//   A[i][k]: lane = i + 16*(k/8), elem = k%8  (8 contiguous k per lane)
//   B[k][j]: lane = j + 16*(k/8), elem = k%8
//   D[r][c]: lane = c + 16*(r/4), reg  = r%4  (C/D verified learn_hip m89/m91)
// Alignment choices: staged col 0 <-> global C0-8 (so A windows start at
// LDS col c0, 16B aligned, band shifted by +3); vertical windows start at
// i=16m. SSTR=88 f16 (176B) and HSTR=56 f16 (112B) give 16B-aligned rows and
// <=2-way (free) LDS bank aliasing on all b128/b64 accesses.

#define IMG_W 512
#define IMG_H 512
#define PLANES 48
#define TX 64
#define TY 32
#define RAD 5
#define NT 256
#define GDX (IMG_W / TX)            // 8
#define GDY (IMG_H / TY)            // 16
#define NBLK (GDX * GDY * PLANES)   // 6144

#define SROWS 48                    // staged rows, i <-> global row R0-5+i
#define SCH   20                    // float4 chunks per row (80 cols staged)
#define SSTR  88                    // f16 row stride (176 B)
#define HSTR  56                    // f16 col stride of transposed H (112 B)
#define GC    (1.f / (2.f * 1.5f * 1.5f))

typedef _Float16 h2 __attribute__((ext_vector_type(2)));
typedef _Float16 h4 __attribute__((ext_vector_type(4)));
typedef _Float16 h8 __attribute__((ext_vector_type(8)));
typedef float f32x4 __attribute__((ext_vector_type(4)));

__device__ __forceinline__ h2 pkrtz(float a, float b) {
    auto t = __builtin_amdgcn_cvt_pkrtz(a, b);
    h2 r;
    __builtin_memcpy(&r, &t, sizeof(r));
    return r;
}

__device__ __forceinline__ h4 pack4(f32x4 a) {
    const h2 lo = pkrtz(a[0], a[1]), hi = pkrtz(a[2], a[3]);
    h4 v;
    v[0] = lo.x; v[1] = lo.y; v[2] = hi.x; v[3] = hi.y;
    return v;
}

__global__ __launch_bounds__(NT, 3) void ssim_tile_kernel(
    const float* __restrict__ x, const float* __restrict__ y,
    float* __restrict__ partials)
{
    __shared__ __align__(16) _Float16 sIn[SROWS * SSTR];   //  8448 B
    __shared__ __align__(16) _Float16 dIn[SROWS * SSTR];   //  8448 B
    __shared__ __align__(16) _Float16 Ht[4 * TX * HSTR];   // 28672 B (S,D,S2,D2)
    __shared__ float wave_sums[NT / 64];
    // total ~45.6 KB -> 3 blocks/CU

    const int tid = threadIdx.x;
    const int l   = tid & 63, wid = tid >> 6;
    const int q   = l >> 4,  fc  = l & 15;

    // ---- f16 weights: normalization + per-lane banded MFMA fragments ----
    float inv, cv;
    {
        float s = 0.f;
        #pragma unroll
        for (int k = 0; k < 11; ++k) {
            const float d = (float)(k - RAD);
            s += expf(-d * d * GC);
        }
        inv = 1.f / s;
        float s2 = 0.f;
        #pragma unroll
        for (int k = 0; k < 11; ++k) {
            const float d = (float)(k - RAD);
            s2 += (float)(_Float16)(expf(-d * d * GC) * inv);
        }
        cv = 1.f / (s2 * s2);        // f16 weight-sum fixup (both passes)
    }

    h8 whB, wvA;                     // horizontal B-frag, vertical A-frag
    #pragma unroll
    for (int e = 0; e < 8; ++e) {
        const int t  = 8 * q + e;
        const int k1 = t - fc - 3;   // horizontal band: w[t-u-3]
        const int k2 = t - fc;       // vertical band:   w[t-u]
        float g1 = 0.f, g2 = 0.f;
        if (k1 >= 0 && k1 <= 10) {
            const float d = (float)(k1 - RAD);
            g1 = expf(-d * d * GC) * inv;
        }
        if (k2 >= 0 && k2 <= 10) {
            const float d = (float)(k2 - RAD);
            g2 = expf(-d * d * GC) * inv;
        }
        whB[e] = (_Float16)g1;
        wvA[e] = (_Float16)g2;
    }

    const int plane = blockIdx.z;
    const float* __restrict__ xp = x + (size_t)plane * IMG_H * IMG_W;
    const float* __restrict__ yp = y + (size_t)plane * IMG_H * IMG_W;
    const int C0 = blockIdx.x * TX;
    const int R0 = blockIdx.y * TY;

    // ---- Stage s=x+y, d=x-y (f16) for rows R0-5..R0+42, cols C0-8..C0+71 ----
    // Out-of-image positions -> 0 (matches the zero-pad conv boundary).
    for (int it = tid; it < SROWS * SCH; it += NT) {       // 960 items
        const int i  = it / SCH;
        const int c  = it - i * SCH;
        const int gr = R0 - RAD + i;
        const int gc = C0 - 8 + 4 * c;                     // float4-aligned
        float4 xa = make_float4(0.f, 0.f, 0.f, 0.f);
        float4 ya = make_float4(0.f, 0.f, 0.f, 0.f);
        if ((unsigned)gr < (unsigned)IMG_H && (unsigned)gc < (unsigned)IMG_W) {
            xa = *(const float4*)(xp + (size_t)gr * IMG_W + gc);
            ya = *(const float4*)(yp + (size_t)gr * IMG_W + gc);
        }
        const h2 x01 = pkrtz(xa.x, xa.y), x23 = pkrtz(xa.z, xa.w);
        const h2 y01 = pkrtz(ya.x, ya.y), y23 = pkrtz(ya.z, ya.w);
        const h2 s01 = x01 + y01, s23 = x23 + y23;         // v_pk_add_f16
        const h2 d01 = x01 - y01, d23 = x23 - y23;
        h4 sv, dv;
        sv[0] = s01.x; sv[1] = s01.y; sv[2] = s23.x; sv[3] = s23.y;
        dv[0] = d01.x; dv[1] = d01.y; dv[2] = d23.x; dv[3] = d23.y;
        *(h4*)&sIn[i * SSTR + 4 * c] = sv;                 // ds_write_b64
        *(h4*)&dIn[i * SSTR + 4 * c] = dv;
    }
    __syncthreads();

    // ---- Horizontal conv via MFMA: wave w owns out-cols c0=16w ----
    // A window: LDS cols c0..c0+31 (global c0+C0-8 .. +23), rows i0..i0+15.
    const int c0 = 16 * wid;
    const f32x4 zz = {0.f, 0.f, 0.f, 0.f};
    #pragma unroll
    for (int i0 = 0; i0 < SROWS; i0 += 16) {               // 3 cells/wave
        const int aoff = (i0 + fc) * SSTR + c0 + 8 * q;
        const h8 sA = *(const h8*)&sIn[aoff];              // ds_read_b128
        const h8 dA = *(const h8*)&dIn[aoff];
        const h8 s2A = sA * sA;                            // v_pk_mul_f16 x4
        const h8 d2A = dA * dA;
        const f32x4 hS  = __builtin_amdgcn_mfma_f32_16x16x32_f16(sA,  whB, zz, 0, 0, 0);
        const f32x4 hD  = __builtin_amdgcn_mfma_f32_16x16x32_f16(dA,  whB, zz, 0, 0, 0);
        const f32x4 hS2 = __builtin_amdgcn_mfma_f32_16x16x32_f16(s2A, whB, zz, 0, 0, 0);
        const f32x4 hD2 = __builtin_amdgcn_mfma_f32_16x16x32_f16(d2A, whB, zz, 0, 0, 0);
        // D: col = fc (out col c0+fc), rows i0+4q+0..3 -> transposed store
        const int hoff = (c0 + fc) * HSTR + i0 + 4 * q;
        *(h4*)&Ht[0 * TX * HSTR + hoff] = pack4(hS);       // ds_write_b64
        *(h4*)&Ht[1 * TX * HSTR + hoff] = pack4(hD);
        *(h4*)&Ht[2 * TX * HSTR + hoff] = pack4(hS2);
        *(h4*)&Ht[3 * TX * HSTR + hoff] = pack4(hD2);
    }
    __syncthreads();

    // ---- Vertical conv via MFMA + SSIM map ----
    float local = 0.f;
    #pragma unroll
    for (int m = 0; m < TY / 16; ++m) {                    // 2 cells/wave
        const int boff = (c0 + fc) * HSTR + 16 * m + 8 * q;
        const f32x4 aS  = __builtin_amdgcn_mfma_f32_16x16x32_f16(
            wvA, *(const h8*)&Ht[0 * TX * HSTR + boff], zz, 0, 0, 0);
        const f32x4 aD  = __builtin_amdgcn_mfma_f32_16x16x32_f16(
            wvA, *(const h8*)&Ht[1 * TX * HSTR + boff], zz, 0, 0, 0);
        const f32x4 aS2 = __builtin_amdgcn_mfma_f32_16x16x32_f16(
            wvA, *(const h8*)&Ht[2 * TX * HSTR + boff], zz, 0, 0, 0);
        const f32x4 aD2 = __builtin_amdgcn_mfma_f32_16x16x32_f16(
            wvA, *(const h8*)&Ht[3 * TX * HSTR + boff], zz, 0, 0, 0);
        // D: out col C0+c0+fc, out rows R0+16m+4q+0..3 (all in-image)
        #pragma unroll
        for (int r = 0; r < 4; ++r) {
            const float mS = aS[r]  * cv, mD = aD[r]  * cv;
            const float eS = aS2[r] * cv, eD = aD2[r] * cv;
            const float ms2 = mS * mS, md2 = mD * mD;
            const float Pm = 0.5f * (ms2 - md2);   // = 2*mu_x*mu_y
            const float Qm = 0.5f * (ms2 + md2);   // = mu_x^2 + mu_y^2
            const float Pe = 0.5f * (eS - eD);     // = 2*E[xy]
            const float Qe = 0.5f * (eS + eD);     // = E[x^2 + y^2]
            const float c1 = 1e-4f, c2 = 9e-4f;
            const float num = (Pm + c1) * (Pe - Pm + c2);
            const float den = (Qm + c1) * (Qe - Qm + c2) + 1e-8f;
            local += num * __builtin_amdgcn_rcpf(den);
        }
    }

    // ---- Block reduction -> one partial per block ----
    #pragma unroll
    for (int off = 32; off > 0; off >>= 1)
        local += __shfl_down(local, off, 64);
    if (l == 0) wave_sums[wid] = local;
    __syncthreads();
    if (tid == 0) {
        const float s = wave_sums[0] + wave_sums[1] + wave_sums[2] + wave_sums[3];
        const int bid = blockIdx.x + GDX * (blockIdx.y + GDY * blockIdx.z);
        partials[bid] = s;
    }
}

__global__ __launch_bounds__(NT) void ssim_finalize_kernel(
    const float* __restrict__ partials, float* __restrict__ out)
{
    const int tid = threadIdx.x;
    double s = 0.0;
    #pragma unroll 4
    for (int i = tid; i < NBLK; i += NT) s += (double)partials[i];
    #pragma unroll
    for (int off = 32; off > 0; off >>= 1)
        s += __shfl_down(s, off, 64);
    __shared__ double ws_[NT / 64];
    const int lane = tid & 63, wv = tid >> 6;
    if (lane == 0) ws_[wv] = s;
    __syncthreads();
    if (tid == 0) {
        const double t = ws_[0] + ws_[1] + ws_[2] + ws_[3];
        const double n = (double)PLANES * IMG_H * IMG_W;
        out[0] = (float)(1.0 - t / n);
    }
}

extern "C" void kernel_launch(void* const* d_in, const int* in_sizes, int n_in,
                              void* d_out, int out_size, void* d_ws, size_t ws_size,
                              hipStream_t stream)
{
    const float* x = (const float*)d_in[0];
    const float* y = (const float*)d_in[1];
    float* out = (float*)d_out;
    float* partials = (float*)d_ws;   // NBLK floats, fully overwritten each call

    dim3 grid(GDX, GDY, PLANES);
    ssim_tile_kernel<<<grid, NT, 0, stream>>>(x, y, partials);
    ssim_finalize_kernel<<<1, NT, 0, stream>>>(partials, out);
}

// Round 2
// 137.519 us; speedup vs baseline: 1.0800x; 1.0800x over previous
//
#include <hip/hip_runtime.h>
#include <math.h>

// SSIM loss, fp32 in, B=16 C=3 H=W=512, 11x11 Gaussian (sigma=1.5), zero pad.
// R11: barrier-free MFMA pipeline.
//  - hconv A-fragments loaded DIRECTLY from global (2x float4 per image per
//    lane; A-layout is lane=row, 8 contiguous k) -> no input LDS staging,
//    no staging barrier. L1/L2 absorbs the halo re-reads.
//  - hconv wave writes Ht cols c0..c0+15; vconv for those cols runs in the
//    SAME wave -> no inter-wave dependency -> zero __syncthreads in the main
//    body (only the tiny final reduction barrier remains).
//  - LDS = transposed Ht only (28.7 KB) -> 5 blocks/CU (was 3 at 46 KB).
//  - weight setup via v_exp_f32 (exp2) + hardcoded normalized constants
//    instead of ~38 libm expf per thread.
// Math identical to R10: S=x+y, D=x-y planes; S2/D2 A-frags are in-register
// pk_mul squares; f16 pipeline with cv weight-sum fixup.
// gfx950 v_mfma_f32_16x16x32_f16 layouts (verified by R10 pass):
//   A[i][k]: lane = i + 16*(k/8), elem = k%8
//   B[k][j]: lane = j + 16*(k/8), elem = k%8
//   D[r][c]: lane = c + 16*(r/4), reg  = r%4

#define IMG_W 512
#define IMG_H 512
#define PLANES 48
#define TX 64
#define TY 32
#define RAD 5
#define NT 256
#define GDX (IMG_W / TX)            // 8
#define GDY (IMG_H / TY)            // 16
#define NBLK (GDX * GDY * PLANES)   // 6144

#define SROWS 48                    // row-window span: R0-5 .. R0+42
#define HSTR  56                    // f16 col stride of transposed H (112 B)
#define INVW  0.26601181f           // 1 / sum(exp(-(k-5)^2/4.5))
#define GC2   0.32059890f           // (1/4.5) * log2(e)

typedef _Float16 h2 __attribute__((ext_vector_type(2)));
typedef _Float16 h4 __attribute__((ext_vector_type(4)));
typedef _Float16 h8 __attribute__((ext_vector_type(8)));
typedef float f32x4 __attribute__((ext_vector_type(4)));

__device__ __forceinline__ float exp2_fast(float a) {
#if __has_builtin(__builtin_amdgcn_exp2f)
    return __builtin_amdgcn_exp2f(a);
#else
    return exp2f(a);
#endif
}

// Normalized f32 Gaussian weight w[idx], idx in [0,10], else 0.
__device__ __forceinline__ float wbandf(int idx) {
    const float fd = (float)(idx - 5);
    const float g = exp2_fast(-(fd * fd) * GC2) * INVW;
    return ((unsigned)idx <= 10u) ? g : 0.f;
}

__device__ __forceinline__ h2 pkrtz(float a, float b) {
    auto t = __builtin_amdgcn_cvt_pkrtz(a, b);
    h2 r;
    __builtin_memcpy(&r, &t, sizeof(r));
    return r;
}

__device__ __forceinline__ h4 pack4(f32x4 a) {
    const h2 lo = pkrtz(a[0], a[1]), hi = pkrtz(a[2], a[3]);
    h4 v;
    v[0] = lo.x; v[1] = lo.y; v[2] = hi.x; v[3] = hi.y;
    return v;
}

// Load s=x+y, d=x-y A-fragment (8 consecutive cols of one row) from global.
template<bool INTERIOR>
__device__ __forceinline__ void load_sd(const float* __restrict__ xp,
                                        const float* __restrict__ yp,
                                        int gr, int gc, h8& sA, h8& dA)
{
    const float4 z4 = make_float4(0.f, 0.f, 0.f, 0.f);
    float4 xa = z4, xb = z4, ya = z4, yb = z4;
    if (INTERIOR || (unsigned)gr < (unsigned)IMG_H) {
        const float* rx = xp + (size_t)gr * IMG_W;
        const float* ry = yp + (size_t)gr * IMG_W;
        // gc is a multiple of 8; each float4 is individually in- or out-of-image
        if (INTERIOR || (unsigned)gc < (unsigned)IMG_W) {
            xa = *(const float4*)(rx + gc);
            ya = *(const float4*)(ry + gc);
        }
        if (INTERIOR || (unsigned)(gc + 4) < (unsigned)IMG_W) {
            xb = *(const float4*)(rx + gc + 4);
            yb = *(const float4*)(ry + gc + 4);
        }
    }
    const h2 xh0 = pkrtz(xa.x, xa.y), xh1 = pkrtz(xa.z, xa.w);
    const h2 xh2 = pkrtz(xb.x, xb.y), xh3 = pkrtz(xb.z, xb.w);
    const h2 yh0 = pkrtz(ya.x, ya.y), yh1 = pkrtz(ya.z, ya.w);
    const h2 yh2 = pkrtz(yb.x, yb.y), yh3 = pkrtz(yb.z, yb.w);
    const h2 s0 = xh0 + yh0, s1 = xh1 + yh1, s2 = xh2 + yh2, s3 = xh3 + yh3;
    const h2 d0 = xh0 - yh0, d1 = xh1 - yh1, d2 = xh2 - yh2, d3 = xh3 - yh3;
    sA[0] = s0.x; sA[1] = s0.y; sA[2] = s1.x; sA[3] = s1.y;
    sA[4] = s2.x; sA[5] = s2.y; sA[6] = s3.x; sA[7] = s3.y;
    dA[0] = d0.x; dA[1] = d0.y; dA[2] = d1.x; dA[3] = d1.y;
    dA[4] = d2.x; dA[5] = d2.y; dA[6] = d3.x; dA[7] = d3.y;
}

// Horizontal conv for this wave's 16 out-cols, all 48 window rows.
template<bool INTERIOR>
__device__ __forceinline__ void hconv_all(
    const float* __restrict__ xp, const float* __restrict__ yp,
    int R0, int gcol, int fc, int q, int c0, h8 whB,
    _Float16* __restrict__ Ht)
{
    const f32x4 zz = {0.f, 0.f, 0.f, 0.f};
    #pragma unroll
    for (int i0 = 0; i0 < SROWS; i0 += 16) {
        h8 sA, dA;
        load_sd<INTERIOR>(xp, yp, R0 - RAD + i0 + fc, gcol, sA, dA);
        const h8 s2A = sA * sA;                     // v_pk_mul_f16
        const h8 d2A = dA * dA;
        const f32x4 hS  = __builtin_amdgcn_mfma_f32_16x16x32_f16(sA,  whB, zz, 0, 0, 0);
        const f32x4 hD  = __builtin_amdgcn_mfma_f32_16x16x32_f16(dA,  whB, zz, 0, 0, 0);
        const f32x4 hS2 = __builtin_amdgcn_mfma_f32_16x16x32_f16(s2A, whB, zz, 0, 0, 0);
        const f32x4 hD2 = __builtin_amdgcn_mfma_f32_16x16x32_f16(d2A, whB, zz, 0, 0, 0);
        // D: col = fc (out col c0+fc), rows i0+4q+0..3 -> transposed store
        const int hoff = (c0 + fc) * HSTR + i0 + 4 * q;
        *(h4*)&Ht[0 * TX * HSTR + hoff] = pack4(hS);     // ds_write_b64
        *(h4*)&Ht[1 * TX * HSTR + hoff] = pack4(hD);
        *(h4*)&Ht[2 * TX * HSTR + hoff] = pack4(hS2);
        *(h4*)&Ht[3 * TX * HSTR + hoff] = pack4(hD2);
    }
}

__global__ __launch_bounds__(NT, 5) void ssim_tile_kernel(
    const float* __restrict__ x, const float* __restrict__ y,
    float* __restrict__ partials)
{
    __shared__ __align__(16) _Float16 Ht[4 * TX * HSTR];   // 28672 B -> 5 blk/CU
    __shared__ float wave_sums[NT / 64];

    const int tid = threadIdx.x;
    const int l   = tid & 63, wid = tid >> 6;
    const int q   = l >> 4,  fc  = l & 15;

    // ---- weights: f16 sum fixup + per-lane banded MFMA fragments ----
    float s2w = 0.f;
    #pragma unroll
    for (int k = 0; k <= 10; ++k) s2w += (float)(_Float16)wbandf(k);
    const float cv = 1.f / (s2w * s2w);

    h8 whB, wvA;                     // horizontal B-frag w[t-u-3], vertical A-frag w[t-u]
    #pragma unroll
    for (int e = 0; e < 8; ++e) whB[e] = (_Float16)wbandf(8 * q + e - fc - 3);
    #pragma unroll
    for (int e = 0; e < 5; ++e) wvA[e] = whB[e + 3];
    #pragma unroll
    for (int e = 5; e < 8; ++e) wvA[e] = (_Float16)wbandf(8 * q + e - fc);

    const int plane = blockIdx.z;
    const float* __restrict__ xp = x + (size_t)plane * IMG_H * IMG_W;
    const float* __restrict__ yp = y + (size_t)plane * IMG_H * IMG_W;
    const int C0 = blockIdx.x * TX;
    const int R0 = blockIdx.y * TY;
    const int c0 = 16 * wid;                 // this wave's out-col base
    const int gcol = C0 + c0 - 8 + 8 * q;    // global col of A-frag start

    const bool interior =
        (blockIdx.x >= 1) && (blockIdx.x <= GDX - 2) &&
        (blockIdx.y >= 1) && (blockIdx.y <= GDY - 2);

    // ---- Horizontal conv (global -> MFMA -> transposed f16 Ht) ----
    if (interior) hconv_all<true >(xp, yp, R0, gcol, fc, q, c0, whB, Ht);
    else          hconv_all<false>(xp, yp, R0, gcol, fc, q, c0, whB, Ht);

    // No barrier: vconv below reads only THIS wave's Ht columns; wave-internal
    // lgkmcnt ordering (compiler-inserted) is sufficient.

    // ---- Vertical conv via MFMA + SSIM map ----
    const f32x4 zz = {0.f, 0.f, 0.f, 0.f};
    float local = 0.f;
    #pragma unroll
    for (int m = 0; m < TY / 16; ++m) {
        const int boff = (c0 + fc) * HSTR + 16 * m + 8 * q;
        const f32x4 aS  = __builtin_amdgcn_mfma_f32_16x16x32_f16(
            wvA, *(const h8*)&Ht[0 * TX * HSTR + boff], zz, 0, 0, 0);
        const f32x4 aD  = __builtin_amdgcn_mfma_f32_16x16x32_f16(
            wvA, *(const h8*)&Ht[1 * TX * HSTR + boff], zz, 0, 0, 0);
        const f32x4 aS2 = __builtin_amdgcn_mfma_f32_16x16x32_f16(
            wvA, *(const h8*)&Ht[2 * TX * HSTR + boff], zz, 0, 0, 0);
        const f32x4 aD2 = __builtin_amdgcn_mfma_f32_16x16x32_f16(
            wvA, *(const h8*)&Ht[3 * TX * HSTR + boff], zz, 0, 0, 0);
        #pragma unroll
        for (int r = 0; r < 4; ++r) {
            const float mS = aS[r]  * cv, mD = aD[r]  * cv;
            const float eS = aS2[r] * cv, eD = aD2[r] * cv;
            const float ms2 = mS * mS, md2 = mD * mD;
            const float Pm = 0.5f * (ms2 - md2);   // = 2*mu_x*mu_y
            const float Qm = 0.5f * (ms2 + md2);   // = mu_x^2 + mu_y^2
            const float Pe = 0.5f * (eS - eD);     // = 2*E[xy]
            const float Qe = 0.5f * (eS + eD);     // = E[x^2 + y^2]
            const float c1 = 1e-4f, c2 = 9e-4f;
            const float num = (Pm + c1) * (Pe - Pm + c2);
            const float den = (Qm + c1) * (Qe - Qm + c2) + 1e-8f;
            local += num * __builtin_amdgcn_rcpf(den);
        }
    }

    // ---- Block reduction -> one partial per block ----
    #pragma unroll
    for (int off = 32; off > 0; off >>= 1)
        local += __shfl_down(local, off, 64);
    if (l == 0) wave_sums[wid] = local;
    __syncthreads();
    if (tid == 0) {
        const float s = wave_sums[0] + wave_sums[1] + wave_sums[2] + wave_sums[3];
        const int bid = blockIdx.x + GDX * (blockIdx.y + GDY * blockIdx.z);
        partials[bid] = s;
    }
}

__global__ __launch_bounds__(NT) void ssim_finalize_kernel(
    const float* __restrict__ partials, float* __restrict__ out)
{
    const int tid = threadIdx.x;
    double s = 0.0;
    #pragma unroll 4
    for (int i = tid; i < NBLK; i += NT) s += (double)partials[i];
    #pragma unroll
    for (int off = 32; off > 0; off >>= 1)
        s += __shfl_down(s, off, 64);
    __shared__ double ws_[NT / 64];
    const int lane = tid & 63, wv = tid >> 6;
    if (lane == 0) ws_[wv] = s;
    __syncthreads();
    if (tid == 0) {
        const double t = ws_[0] + ws_[1] + ws_[2] + ws_[3];
        const double n = (double)PLANES * IMG_H * IMG_W;
        out[0] = (float)(1.0 - t / n);
    }
}

extern "C" void kernel_launch(void* const* d_in, const int* in_sizes, int n_in,
                              void* d_out, int out_size, void* d_ws, size_t ws_size,
                              hipStream_t stream)
{
    const float* x = (const float*)d_in[0];
    const float* y = (const float*)d_in[1];
    float* out = (float*)d_out;
    float* partials = (float*)d_ws;   // NBLK floats, fully overwritten each call

    dim3 grid(GDX, GDY, PLANES);
    ssim_tile_kernel<<<grid, NT, 0, stream>>>(x, y, partials);
    ssim_finalize_kernel<<<1, NT, 0, stream>>>(partials, out);
}

// Round 3
// 135.875 us; speedup vs baseline: 1.0931x; 1.0121x over previous
//
#include <hip/hip_runtime.h>
#include <math.h>

// SSIM loss, fp32 in, B=16 C=3 H=W=512, 11x11 Gaussian (sigma=1.5), zero pad.
// R12: latency restructure of R11 (barrier-free MFMA pipeline).
//  - ALL 12 float4 global loads per lane issued up front into named register
//    arrays (static indices -> stays in VGPRs); one vmcnt latency exposure
//    instead of three serialized batches (R11 at 44 VGPRs was load->use
//    serialized; counters showed the latency-bound quadrant: VALU 40%,
//    MFMA 6%, HBM 23%, occupancy 38%).
//  - weight setup (22x v_exp chain) moved AFTER load issue so it executes
//    under the in-flight loads.
//  - everything else identical to R11: direct-from-global A-fragments,
//    same-wave hconv->Ht->vconv (zero main-body barriers), 28.7 KB LDS ->
//    5 blocks/CU, f16 pipeline with cv weight-sum fixup.
// gfx950 v_mfma_f32_16x16x32_f16 layouts (verified R10/R11 pass):
//   A[i][k]: lane = i + 16*(k/8), elem = k%8
//   B[k][j]: lane = j + 16*(k/8), elem = k%8
//   D[r][c]: lane = c + 16*(r/4), reg  = r%4

#define IMG_W 512
#define IMG_H 512
#define PLANES 48
#define TX 64
#define TY 32
#define RAD 5
#define NT 256
#define GDX (IMG_W / TX)            // 8
#define GDY (IMG_H / TY)            // 16
#define NBLK (GDX * GDY * PLANES)   // 6144

#define SROWS 48                    // row-window span: R0-5 .. R0+42
#define HSTR  56                    // f16 col stride of transposed H (112 B)
#define INVW  0.26601181f           // 1 / sum(exp(-(k-5)^2/4.5))
#define GC2   0.32059890f           // (1/4.5) * log2(e)

typedef _Float16 h2 __attribute__((ext_vector_type(2)));
typedef _Float16 h4 __attribute__((ext_vector_type(4)));
typedef _Float16 h8 __attribute__((ext_vector_type(8)));
typedef float f32x4 __attribute__((ext_vector_type(4)));

__device__ __forceinline__ float exp2_fast(float a) {
#if __has_builtin(__builtin_amdgcn_exp2f)
    return __builtin_amdgcn_exp2f(a);
#else
    return exp2f(a);
#endif
}

// Normalized f32 Gaussian weight w[idx], idx in [0,10], else 0.
__device__ __forceinline__ float wbandf(int idx) {
    const float fd = (float)(idx - 5);
    const float g = exp2_fast(-(fd * fd) * GC2) * INVW;
    return ((unsigned)idx <= 10u) ? g : 0.f;
}

__device__ __forceinline__ h2 pkrtz(float a, float b) {
    auto t = __builtin_amdgcn_cvt_pkrtz(a, b);
    h2 r;
    __builtin_memcpy(&r, &t, sizeof(r));
    return r;
}

__device__ __forceinline__ h4 pack4(f32x4 a) {
    const h2 lo = pkrtz(a[0], a[1]), hi = pkrtz(a[2], a[3]);
    h4 v;
    v[0] = lo.x; v[1] = lo.y; v[2] = hi.x; v[3] = hi.y;
    return v;
}

__global__ __launch_bounds__(NT, 5) void ssim_tile_kernel(
    const float* __restrict__ x, const float* __restrict__ y,
    float* __restrict__ partials)
{
    __shared__ __align__(16) _Float16 Ht[4 * TX * HSTR];   // 28672 B -> 5 blk/CU
    __shared__ float wave_sums[NT / 64];

    const int tid = threadIdx.x;
    const int l   = tid & 63, wid = tid >> 6;
    const int q   = l >> 4,  fc  = l & 15;

    const int plane = blockIdx.z;
    const float* __restrict__ xp = x + (size_t)plane * IMG_H * IMG_W;
    const float* __restrict__ yp = y + (size_t)plane * IMG_H * IMG_W;
    const int C0 = blockIdx.x * TX;
    const int R0 = blockIdx.y * TY;
    const int c0 = 16 * wid;                 // this wave's out-col base
    const int gcol = C0 + c0 - 8 + 8 * q;    // global col of A-frag start

    const bool interior =
        (blockIdx.x >= 1) && (blockIdx.x <= GDX - 2) &&
        (blockIdx.y >= 1) && (blockIdx.y <= GDY - 2);

    // ---- Issue ALL global loads up front (one latency exposure) ----
    float4 XA[3], XB[3], YA[3], YB[3];
    if (interior) {
        #pragma unroll
        for (int t = 0; t < 3; ++t) {
            const float* rx = xp + (size_t)(R0 - RAD + 16 * t + fc) * IMG_W + gcol;
            const float* ry = yp + (size_t)(R0 - RAD + 16 * t + fc) * IMG_W + gcol;
            XA[t] = *(const float4*)rx;
            XB[t] = *(const float4*)(rx + 4);
            YA[t] = *(const float4*)ry;
            YB[t] = *(const float4*)(ry + 4);
        }
    } else {
        const float4 z4 = make_float4(0.f, 0.f, 0.f, 0.f);
        #pragma unroll
        for (int t = 0; t < 3; ++t) {
            XA[t] = z4; XB[t] = z4; YA[t] = z4; YB[t] = z4;
            const int gr = R0 - RAD + 16 * t + fc;
            if ((unsigned)gr < (unsigned)IMG_H) {
                const float* rx = xp + (size_t)gr * IMG_W;
                const float* ry = yp + (size_t)gr * IMG_W;
                if ((unsigned)gcol < (unsigned)IMG_W) {
                    XA[t] = *(const float4*)(rx + gcol);
                    YA[t] = *(const float4*)(ry + gcol);
                }
                if ((unsigned)(gcol + 4) < (unsigned)IMG_W) {
                    XB[t] = *(const float4*)(rx + gcol + 4);
                    YB[t] = *(const float4*)(ry + gcol + 4);
                }
            }
        }
    }

    // ---- Weight setup (executes under the in-flight loads) ----
    float s2w = 0.f;
    #pragma unroll
    for (int k = 0; k <= 10; ++k) s2w += (float)(_Float16)wbandf(k);
    const float cv = 1.f / (s2w * s2w);

    h8 whB, wvA;                 // horizontal B-frag w[t-u-3], vertical A-frag w[t-u]
    #pragma unroll
    for (int e = 0; e < 8; ++e) whB[e] = (_Float16)wbandf(8 * q + e - fc - 3);
    #pragma unroll
    for (int e = 0; e < 5; ++e) wvA[e] = whB[e + 3];
    #pragma unroll
    for (int e = 5; e < 8; ++e) wvA[e] = (_Float16)wbandf(8 * q + e - fc);

    // ---- Horizontal conv (regs -> MFMA -> transposed f16 Ht) ----
    const f32x4 zz = {0.f, 0.f, 0.f, 0.f};
    #pragma unroll
    for (int t = 0; t < 3; ++t) {
        const h2 xh0 = pkrtz(XA[t].x, XA[t].y), xh1 = pkrtz(XA[t].z, XA[t].w);
        const h2 xh2 = pkrtz(XB[t].x, XB[t].y), xh3 = pkrtz(XB[t].z, XB[t].w);
        const h2 yh0 = pkrtz(YA[t].x, YA[t].y), yh1 = pkrtz(YA[t].z, YA[t].w);
        const h2 yh2 = pkrtz(YB[t].x, YB[t].y), yh3 = pkrtz(YB[t].z, YB[t].w);
        const h2 s0 = xh0 + yh0, s1 = xh1 + yh1, s2 = xh2 + yh2, s3 = xh3 + yh3;
        const h2 d0 = xh0 - yh0, d1 = xh1 - yh1, d2 = xh2 - yh2, d3 = xh3 - yh3;
        h8 sA, dA;
        sA[0] = s0.x; sA[1] = s0.y; sA[2] = s1.x; sA[3] = s1.y;
        sA[4] = s2.x; sA[5] = s2.y; sA[6] = s3.x; sA[7] = s3.y;
        dA[0] = d0.x; dA[1] = d0.y; dA[2] = d1.x; dA[3] = d1.y;
        dA[4] = d2.x; dA[5] = d2.y; dA[6] = d3.x; dA[7] = d3.y;
        const h8 s2A = sA * sA;                     // v_pk_mul_f16
        const h8 d2A = dA * dA;
        const f32x4 hS  = __builtin_amdgcn_mfma_f32_16x16x32_f16(sA,  whB, zz, 0, 0, 0);
        const f32x4 hD  = __builtin_amdgcn_mfma_f32_16x16x32_f16(dA,  whB, zz, 0, 0, 0);
        const f32x4 hS2 = __builtin_amdgcn_mfma_f32_16x16x32_f16(s2A, whB, zz, 0, 0, 0);
        const f32x4 hD2 = __builtin_amdgcn_mfma_f32_16x16x32_f16(d2A, whB, zz, 0, 0, 0);
        // D: col = fc (out col c0+fc), rows 16t+4q+0..3 -> transposed store
        const int hoff = (c0 + fc) * HSTR + 16 * t + 4 * q;
        *(h4*)&Ht[0 * TX * HSTR + hoff] = pack4(hS);     // ds_write_b64
        *(h4*)&Ht[1 * TX * HSTR + hoff] = pack4(hD);
        *(h4*)&Ht[2 * TX * HSTR + hoff] = pack4(hS2);
        *(h4*)&Ht[3 * TX * HSTR + hoff] = pack4(hD2);
    }

    // No barrier: vconv reads only THIS wave's Ht columns; wave-internal
    // lgkmcnt ordering (compiler-inserted) is sufficient.

    // ---- Vertical conv via MFMA + SSIM map ----
    float local = 0.f;
    #pragma unroll
    for (int m = 0; m < TY / 16; ++m) {
        const int boff = (c0 + fc) * HSTR + 16 * m + 8 * q;
        const f32x4 aS  = __builtin_amdgcn_mfma_f32_16x16x32_f16(
            wvA, *(const h8*)&Ht[0 * TX * HSTR + boff], zz, 0, 0, 0);
        const f32x4 aD  = __builtin_amdgcn_mfma_f32_16x16x32_f16(
            wvA, *(const h8*)&Ht[1 * TX * HSTR + boff], zz, 0, 0, 0);
        const f32x4 aS2 = __builtin_amdgcn_mfma_f32_16x16x32_f16(
            wvA, *(const h8*)&Ht[2 * TX * HSTR + boff], zz, 0, 0, 0);
        const f32x4 aD2 = __builtin_amdgcn_mfma_f32_16x16x32_f16(
            wvA, *(const h8*)&Ht[3 * TX * HSTR + boff], zz, 0, 0, 0);
        #pragma unroll
        for (int r = 0; r < 4; ++r) {
            const float mS = aS[r]  * cv, mD = aD[r]  * cv;
            const float eS = aS2[r] * cv, eD = aD2[r] * cv;
            const float ms2 = mS * mS, md2 = mD * mD;
            const float Pm = 0.5f * (ms2 - md2);   // = 2*mu_x*mu_y
            const float Qm = 0.5f * (ms2 + md2);   // = mu_x^2 + mu_y^2
            const float Pe = 0.5f * (eS - eD);     // = 2*E[xy]
            const float Qe = 0.5f * (eS + eD);     // = E[x^2 + y^2]
            const float c1 = 1e-4f, c2 = 9e-4f;
            const float num = (Pm + c1) * (Pe - Pm + c2);
            const float den = (Qm + c1) * (Qe - Qm + c2) + 1e-8f;
            local += num * __builtin_amdgcn_rcpf(den);
        }
    }

    // ---- Block reduction -> one partial per block ----
    #pragma unroll
    for (int off = 32; off > 0; off >>= 1)
        local += __shfl_down(local, off, 64);
    if (l == 0) wave_sums[wid] = local;
    __syncthreads();
    if (tid == 0) {
        const float s = wave_sums[0] + wave_sums[1] + wave_sums[2] + wave_sums[3];
        const int bid = blockIdx.x + GDX * (blockIdx.y + GDY * blockIdx.z);
        partials[bid] = s;
    }
}

__global__ __launch_bounds__(NT) void ssim_finalize_kernel(
    const float* __restrict__ partials, float* __restrict__ out)
{
    const int tid = threadIdx.x;
    double s = 0.0;
    #pragma unroll 4
    for (int i = tid; i < NBLK; i += NT) s += (double)partials[i];
    #pragma unroll
    for (int off = 32; off > 0; off >>= 1)
        s += __shfl_down(s, off, 64);
    __shared__ double ws_[NT / 64];
    const int lane = tid & 63, wv = tid >> 6;
    if (lane == 0) ws_[wv] = s;
    __syncthreads();
    if (tid == 0) {
        const double t = ws_[0] + ws_[1] + ws_[2] + ws_[3];
        const double n = (double)PLANES * IMG_H * IMG_W;
        out[0] = (float)(1.0 - t / n);
    }
}

extern "C" void kernel_launch(void* const* d_in, const int* in_sizes, int n_in,
                              void* d_out, int out_size, void* d_ws, size_t ws_size,
                              hipStream_t stream)
{
    const float* x = (const float*)d_in[0];
    const float* y = (const float*)d_in[1];
    float* out = (float*)d_out;
    float* partials = (float*)d_ws;   // NBLK floats, fully overwritten each call

    dim3 grid(GDX, GDY, PLANES);
    ssim_tile_kernel<<<grid, NT, 0, stream>>>(x, y, partials);
    ssim_finalize_kernel<<<1, NT, 0, stream>>>(partials, out);
}

// Round 4
// 132.859 us; speedup vs baseline: 1.1179x; 1.0227x over previous
//
#include <hip/hip_runtime.h>
#include <math.h>

// SSIM loss, fp32 in, B=16 C=3 H=W=512, 11x11 Gaussian (sigma=1.5), zero pad.
// R13: column-strip streaming MFMA pipeline.
//  - block = 64 cols x 128 out rows; per wave 9 hconv + 8 vconv 16-row chunks,
//    software-pipelined with a 3-deep global-load buffer (issue chunk c+3
//    while computing chunk c) -> ~2 iterations of latency cover per load.
//  - Ht is a 3-slot ring (vconv m reads H chunks m,m+1 only) -> LDS stays
//    28.7 KB despite the 4x taller tile. Barrier-free main body (same-wave
//    producer/consumer, ring slots distinct).
//  - boundary handling is FREE: SRSRC buffer loads (llvm.amdgcn.raw.buffer.
//    load.v4f32, CK's proven binding) return 0 hardware-side for OOB rows
//    (voffset out of [0,1MB)); col-OOB lanes get a permanently-OOB voffset.
//    One uniform code path, no masks, no interior/border templates.
// Math identical to R10-R12 (S=x+y, D=x-y planes, f16 pipeline, cv fixup).
// gfx950 v_mfma_f32_16x16x32_f16 layouts (verified R10-R12 pass):
//   A[i][k]: lane = i + 16*(k/8), elem = k%8
//   B[k][j]: lane = j + 16*(k/8), elem = k%8
//   D[r][c]: lane = c + 16*(r/4), reg  = r%4

#define IMG_W 512
#define IMG_H 512
#define PLANES 48
#define TX 64
#define TYS 128
#define RAD 5
#define NT 256
#define GDX (IMG_W / TX)            // 8
#define GDY (IMG_H / TYS)           // 4
#define NBLK (GDX * GDY * PLANES)   // 1536
#define NCH 9                       // hconv 16-row chunks (144 H rows)
#define NCV 8                       // vconv 16-row chunks (128 out rows)
#define CSTRH 56                    // Ht col stride, f16 units (112 B: 3 slots*16 + 8 pad)
#define PSTRH 3584                  // Ht plane stride, f16 units (64*56)
#define NUMREC (IMG_W * IMG_H * 4)  // SRD num_records (bytes)
#define CHSTEP (16 * IMG_W * 4)     // voffset step per 16-row chunk (32768)
#define INVW  0.26601181f           // 1 / sum(exp(-(k-5)^2/4.5))
#define GC2   0.32059890f           // (1/4.5) * log2(e)

typedef _Float16 h2 __attribute__((ext_vector_type(2)));
typedef _Float16 h4 __attribute__((ext_vector_type(4)));
typedef _Float16 h8 __attribute__((ext_vector_type(8)));
typedef float f32x4 __attribute__((ext_vector_type(4)));
typedef int i32x4 __attribute__((ext_vector_type(4)));

// CK-style direct binding to the raw buffer-load intrinsic: hardware
// bounds-check vs num_records; OOB lanes read 0. Compiler tracks vmcnt.
__device__ f32x4 buf_ld_x4(i32x4 srsrc, int voffset, int soffset, int aux)
    __asm("llvm.amdgcn.raw.buffer.load.v4f32");

__device__ __forceinline__ i32x4 make_srd(const float* p) {
    union { i32x4 v; struct { const float* p; unsigned rng; unsigned cfg; } s; } u;
    u.s.p = p; u.s.rng = NUMREC; u.s.cfg = 0x00020000u;
    return u.v;
}

__device__ __forceinline__ float exp2_fast(float a) {
#if __has_builtin(__builtin_amdgcn_exp2f)
    return __builtin_amdgcn_exp2f(a);
#else
    return exp2f(a);
#endif
}

// Normalized f32 Gaussian weight w[idx], idx in [0,10], else 0.
__device__ __forceinline__ float wbandf(int idx) {
    const float fd = (float)(idx - 5);
    const float g = exp2_fast(-(fd * fd) * GC2) * INVW;
    return ((unsigned)idx <= 10u) ? g : 0.f;
}

__device__ __forceinline__ h2 pkrtz(float a, float b) {
    auto t = __builtin_amdgcn_cvt_pkrtz(a, b);
    h2 r;
    __builtin_memcpy(&r, &t, sizeof(r));
    return r;
}

__device__ __forceinline__ h4 pack4(f32x4 a) {
    const h2 lo = pkrtz(a[0], a[1]), hi = pkrtz(a[2], a[3]);
    h4 v;
    v[0] = lo.x; v[1] = lo.y; v[2] = hi.x; v[3] = hi.y;
    return v;
}

// One 16-row hconv chunk: regs -> s/d/s2/d2 MFMA -> transposed f16 Ht slot.
__device__ __forceinline__ void hconv_chunk(
    f32x4 xa, f32x4 xb, f32x4 ya, f32x4 yb, h8 whB,
    _Float16* wp)    // = Ht + col*CSTRH + 4*q + slot*16
{
    const f32x4 zz = {0.f, 0.f, 0.f, 0.f};
    const h2 xh0 = pkrtz(xa[0], xa[1]), xh1 = pkrtz(xa[2], xa[3]);
    const h2 xh2 = pkrtz(xb[0], xb[1]), xh3 = pkrtz(xb[2], xb[3]);
    const h2 yh0 = pkrtz(ya[0], ya[1]), yh1 = pkrtz(ya[2], ya[3]);
    const h2 yh2 = pkrtz(yb[0], yb[1]), yh3 = pkrtz(yb[2], yb[3]);
    const h2 s0 = xh0 + yh0, s1 = xh1 + yh1, s2 = xh2 + yh2, s3 = xh3 + yh3;
    const h2 d0 = xh0 - yh0, d1 = xh1 - yh1, d2 = xh2 - yh2, d3 = xh3 - yh3;
    h8 sA, dA;
    sA[0] = s0.x; sA[1] = s0.y; sA[2] = s1.x; sA[3] = s1.y;
    sA[4] = s2.x; sA[5] = s2.y; sA[6] = s3.x; sA[7] = s3.y;
    dA[0] = d0.x; dA[1] = d0.y; dA[2] = d1.x; dA[3] = d1.y;
    dA[4] = d2.x; dA[5] = d2.y; dA[6] = d3.x; dA[7] = d3.y;
    const h8 s2A = sA * sA;                       // v_pk_mul_f16
    const h8 d2A = dA * dA;
    const f32x4 hS  = __builtin_amdgcn_mfma_f32_16x16x32_f16(sA,  whB, zz, 0, 0, 0);
    const f32x4 hD  = __builtin_amdgcn_mfma_f32_16x16x32_f16(dA,  whB, zz, 0, 0, 0);
    const f32x4 hS2 = __builtin_amdgcn_mfma_f32_16x16x32_f16(s2A, whB, zz, 0, 0, 0);
    const f32x4 hD2 = __builtin_amdgcn_mfma_f32_16x16x32_f16(d2A, whB, zz, 0, 0, 0);
    *(h4*)(wp + 0 * PSTRH) = pack4(hS);           // ds_write_b64, imm plane offs
    *(h4*)(wp + 1 * PSTRH) = pack4(hD);
    *(h4*)(wp + 2 * PSTRH) = pack4(hS2);
    *(h4*)(wp + 3 * PSTRH) = pack4(hD2);
}

__global__ __launch_bounds__(NT, 4) void ssim_tile_kernel(
    const float* __restrict__ x, const float* __restrict__ y,
    float* __restrict__ partials)
{
    __shared__ __align__(16) _Float16 Ht[4 * TX * CSTRH];   // 28672 B
    __shared__ float wave_sums[NT / 64];

    const int tid = threadIdx.x;
    const int l = tid & 63, wid = tid >> 6;
    const int q = l >> 4, fc = l & 15;
    const int qh = q >> 1, ql = q & 1;

    const int plane = blockIdx.z;
    const i32x4 srdx = make_srd(x + (size_t)plane * IMG_H * IMG_W);
    const i32x4 srdy = make_srd(y + (size_t)plane * IMG_H * IMG_W);
    const int C0 = blockIdx.x * TX;
    const int R0 = blockIdx.y * TYS;
    const int c0 = 16 * wid;
    const int col = c0 + fc;
    const int gcol = C0 + c0 - 8 + 8 * q;       // A-frag global col start
    const int gr0 = R0 - RAD + fc;              // chunk-0 global row
    // Row OOB (gr<0 or >=512) -> voffset outside [0,NUMREC) -> HW returns 0.
    // Col OOB lanes (gcol=-8 or 512): force permanently-OOB voffset.
    int voff = ((unsigned)gcol < (unsigned)IMG_W)
             ? ((gr0 << 11) + (gcol << 2)) : 0x60000000;

    // ---- Issue chunks 0..2 (3-deep pipeline) ----
    f32x4 LXA[3], LXB[3], LYA[3], LYB[3];
    #pragma unroll
    for (int c = 0; c < 3; ++c) {
        LXA[c] = buf_ld_x4(srdx, voff, 0, 0);
        LXB[c] = buf_ld_x4(srdx, voff, 16, 0);
        LYA[c] = buf_ld_x4(srdy, voff, 0, 0);
        LYB[c] = buf_ld_x4(srdy, voff, 16, 0);
        voff += CHSTEP;
    }

    // ---- Weight setup (executes under the in-flight loads) ----
    float s2w = 0.f;
    #pragma unroll
    for (int k = 0; k <= 10; ++k) s2w += (float)(_Float16)wbandf(k);
    const float cv = 1.f / (s2w * s2w);

    h8 whB, wvA;                 // horizontal B-frag w[t-u-3], vertical A-frag w[t-u]
    #pragma unroll
    for (int e = 0; e < 8; ++e) whB[e] = (_Float16)wbandf(8 * q + e - fc - 3);
    #pragma unroll
    for (int e = 0; e < 5; ++e) wvA[e] = whB[e + 3];
    #pragma unroll
    for (int e = 5; e < 8; ++e) wvA[e] = (_Float16)wbandf(8 * q + e - fc);

    // LDS bases (f16 units)
    _Float16* const hw = Ht + col * CSTRH + 4 * q;       // hconv write (+slot*16)
    const int rb = col * CSTRH + 8 * ql;                 // vconv read  (+slot*16)

    // ---- Prologue: hconv chunks 0,1 ----
    hconv_chunk(LXA[0], LXB[0], LYA[0], LYB[0], whB, hw + 0 * 16);
    hconv_chunk(LXA[1], LXB[1], LYA[1], LYB[1], whB, hw + 1 * 16);

    // ---- Main loop: issue c=m+3 | vconv m | hconv c=m+2 ----
    const f32x4 zz = {0.f, 0.f, 0.f, 0.f};
    float local = 0.f;
    int vslot = qh;                              // (m + qh) % 3 at m = 0
    #pragma unroll
    for (int m = 0; m < NCV; ++m) {
        if (m + 3 < NCH) {                       // chunk m+3 -> buf (m%3)
            LXA[m % 3] = buf_ld_x4(srdx, voff, 0, 0);
            LXB[m % 3] = buf_ld_x4(srdx, voff, 16, 0);
            LYA[m % 3] = buf_ld_x4(srdy, voff, 0, 0);
            LYB[m % 3] = buf_ld_x4(srdy, voff, 16, 0);
            voff += CHSTEP;
        }

        // vconv m: reads H chunks m (slot m%3) and m+1; per-lane slot = vslot
        const _Float16* rp = Ht + rb + vslot * 16;
        const f32x4 aS  = __builtin_amdgcn_mfma_f32_16x16x32_f16(
            wvA, *(const h8*)(rp + 0 * PSTRH), zz, 0, 0, 0);
        const f32x4 aD  = __builtin_amdgcn_mfma_f32_16x16x32_f16(
            wvA, *(const h8*)(rp + 1 * PSTRH), zz, 0, 0, 0);
        const f32x4 aS2 = __builtin_amdgcn_mfma_f32_16x16x32_f16(
            wvA, *(const h8*)(rp + 2 * PSTRH), zz, 0, 0, 0);
        const f32x4 aD2 = __builtin_amdgcn_mfma_f32_16x16x32_f16(
            wvA, *(const h8*)(rp + 3 * PSTRH), zz, 0, 0, 0);
        vslot = (vslot == 2) ? 0 : vslot + 1;

        #pragma unroll
        for (int r = 0; r < 4; ++r) {
            const float mS = aS[r]  * cv, mD = aD[r]  * cv;
            const float eS = aS2[r] * cv, eD = aD2[r] * cv;
            const float ms2 = mS * mS, md2 = mD * mD;
            const float Pm = 0.5f * (ms2 - md2);   // = 2*mu_x*mu_y
            const float Qm = 0.5f * (ms2 + md2);   // = mu_x^2 + mu_y^2
            const float Pe = 0.5f * (eS - eD);     // = 2*E[xy]
            const float Qe = 0.5f * (eS + eD);     // = E[x^2 + y^2]
            const float c1 = 1e-4f, c2 = 9e-4f;
            const float num = (Pm + c1) * (Pe - Pm + c2);
            const float den = (Qm + c1) * (Qe - Qm + c2) + 1e-8f;
            local += num * __builtin_amdgcn_rcpf(den);
        }

        if (m + 2 < NCH)                         // hconv chunk m+2 from buf
            hconv_chunk(LXA[(m + 2) % 3], LXB[(m + 2) % 3],
                        LYA[(m + 2) % 3], LYB[(m + 2) % 3],
                        whB, hw + ((m + 2) % 3) * 16);
    }

    // ---- Block reduction -> one partial per block ----
    #pragma unroll
    for (int off = 32; off > 0; off >>= 1)
        local += __shfl_down(local, off, 64);
    if (l == 0) wave_sums[wid] = local;
    __syncthreads();
    if (tid == 0) {
        const float s = wave_sums[0] + wave_sums[1] + wave_sums[2] + wave_sums[3];
        const int bid = blockIdx.x + GDX * (blockIdx.y + GDY * blockIdx.z);
        partials[bid] = s;
    }
}

__global__ __launch_bounds__(NT) void ssim_finalize_kernel(
    const float* __restrict__ partials, float* __restrict__ out)
{
    const int tid = threadIdx.x;
    double s = 0.0;
    #pragma unroll 4
    for (int i = tid; i < NBLK; i += NT) s += (double)partials[i];
    #pragma unroll
    for (int off = 32; off > 0; off >>= 1)
        s += __shfl_down(s, off, 64);
    __shared__ double ws_[NT / 64];
    const int lane = tid & 63, wv = tid >> 6;
    if (lane == 0) ws_[wv] = s;
    __syncthreads();
    if (tid == 0) {
        const double t = ws_[0] + ws_[1] + ws_[2] + ws_[3];
        const double n = (double)PLANES * IMG_H * IMG_W;
        out[0] = (float)(1.0 - t / n);
    }
}

extern "C" void kernel_launch(void* const* d_in, const int* in_sizes, int n_in,
                              void* d_out, int out_size, void* d_ws, size_t ws_size,
                              hipStream_t stream)
{
    const float* x = (const float*)d_in[0];
    const float* y = (const float*)d_in[1];
    float* out = (float*)d_out;
    float* partials = (float*)d_ws;   // NBLK floats, fully overwritten each call

    dim3 grid(GDX, GDY, PLANES);
    ssim_tile_kernel<<<grid, NT, 0, stream>>>(x, y, partials);
    ssim_finalize_kernel<<<1, NT, 0, stream>>>(partials, out);
}